// Round 8
// baseline (1724.327 us; speedup 1.0000x reference)
//
#include <hip/hip_runtime.h>
#include <hip/hip_fp16.h>
#include <cstdint>
#include <cstddef>

#define N_NODES 100000
#define N_EDGES 1600000
#define H 128
#define L_LAYERS 5
#define G_GRAPHS 128
#define OUT_F 128
#define BN_EPS 1e-5f
#define SCAN_BLOCKS 98   // ceil(100000/1024)
#define AGG_BLOCKS 2048
#define NPW 13           // nodes per wave: ceil(100000 / (2048*4))

typedef _Float16 half8_t __attribute__((ext_vector_type(8)));
typedef float floatx4 __attribute__((ext_vector_type(4)));

__device__ __forceinline__ float frelu(float x) { return fmaxf(x, 0.0f); }

// ================= preprocessing =================

__global__ void count_kernel(const int* __restrict__ erow, const int* __restrict__ ecol,
                             int* __restrict__ degcnt, int* __restrict__ hist) {
    int e = blockIdx.x * 256 + threadIdx.x;  // E divisible by 256
    atomicAdd(&degcnt[erow[e]], 1);
    atomicAdd(&hist[ecol[e]], 1);
}

__global__ void finish_deg(const int* __restrict__ degcnt, float* __restrict__ dis,
                           float* __restrict__ invdeg) {
    int i = blockIdx.x * 256 + threadIdx.x;
    if (i < N_NODES) {
        float d = (float)degcnt[i] + 1.0f;
        dis[i] = rsqrtf(d);
        invdeg[i] = 1.0f / d;
    }
}

// ---- two-level scan ----
__global__ __launch_bounds__(1024) void scan_part(const int* __restrict__ hist,
                                                  int* __restrict__ rowptr,
                                                  int* __restrict__ blocksum) {
    int t = threadIdx.x;
    int i = blockIdx.x * 1024 + t;
    int orig = (i < N_NODES) ? hist[i] : 0;
    int v = orig;
#pragma unroll
    for (int off = 1; off < 64; off <<= 1) {
        int u = __shfl_up(v, off);
        if ((t & 63) >= off) v += u;
    }
    __shared__ int wsum[16];
    int wid = t >> 6;
    if ((t & 63) == 63) wsum[wid] = v;
    __syncthreads();
    int woff = 0;
#pragma unroll
    for (int w = 0; w < 16; w++)
        if (w < wid) woff += wsum[w];
    int incl = v + woff;
    if (i < N_NODES) rowptr[i] = incl - orig;
    if (t == 1023) blocksum[blockIdx.x] = incl;
}

__global__ __launch_bounds__(128) void scan_block(const int* __restrict__ blocksum,
                                                  int* __restrict__ blockoff,
                                                  int* __restrict__ rowptr) {
    int t = threadIdx.x;
    int orig = (t < SCAN_BLOCKS) ? blocksum[t] : 0;
    int v = orig;
#pragma unroll
    for (int off = 1; off < 64; off <<= 1) {
        int u = __shfl_up(v, off);
        if ((t & 63) >= off) v += u;
    }
    __shared__ int w0;
    if (t == 63) w0 = v;
    __syncthreads();
    if (t >= 64) v += w0;
    if (t < SCAN_BLOCKS) blockoff[t] = v - orig;
    if (t == 0) rowptr[N_NODES] = N_EDGES;
}

__global__ __launch_bounds__(1024) void scan_add(int* __restrict__ rowptr,
                                                 const int* __restrict__ blockoff,
                                                 int* __restrict__ cursor) {
    int i = blockIdx.x * 1024 + threadIdx.x;
    if (i < N_NODES) {
        int v = rowptr[i] + blockoff[blockIdx.x];
        rowptr[i] = v;
        cursor[i] = v;
    }
}

// permute edge payloads into col-sorted order
__global__ void scatter_kernel(const int* __restrict__ erow, const int* __restrict__ ecol,
                               const float* __restrict__ ea, const float* __restrict__ dis,
                               int* __restrict__ cursor,
                               float* __restrict__ ea8, int* __restrict__ rows) {
    int e = blockIdx.x * 256 + threadIdx.x;
    int c = ecol[e];
    int r = erow[e];
    float nrm = dis[r] * dis[c];
    int pos = atomicAdd(&cursor[c], 1);
    const float* p = ea + (size_t)e * 7;
    float a0 = p[0], a1 = p[1], a2 = p[2], a3 = p[3], a4 = p[4], a5 = p[5], a6 = p[6];
    float* dst = ea8 + (size_t)pos * 8;
    *(float4*)dst = make_float4(a0, a1, a2, a3);
    *(float4*)(dst + 4) = make_float4(a4, a5, a6, nrm);
    rows[pos] = r;
}

// ================= xl = act(h) @ W + b  via MFMA f16 =================
__global__ __launch_bounds__(256) void gemm_xl(const __half* __restrict__ hsrc,
                                               const int* __restrict__ xidx,
                                               const float* __restrict__ nemb,
                                               const float* __restrict__ colsum_p,
                                               const float* __restrict__ colsumsq_p,
                                               const float* __restrict__ gamma_p,
                                               const float* __restrict__ beta_p,
                                               const float* __restrict__ Wl,
                                               const float* __restrict__ bl,
                                               __half* __restrict__ xlo, int mode) {
    __shared__ half8_t sB[2048];          // [ct][ks][lane] fragments, 32 KB
    __shared__ float sScale[H], sShift[H];
    int t = threadIdx.x;
    if (mode == 1 && t < H) {
        float mean = colsum_p[t] * (1.0f / N_NODES);
        float var = colsumsq_p[t] * (1.0f / N_NODES) - mean * mean;
        float s = gamma_p[t] * rsqrtf(var + BN_EPS);
        sScale[t] = s;
        sShift[t] = beta_p[t] - mean * s;
    }
    // stage W as B-fragments
    for (int idx = t; idx < 2048; idx += 256) {
        int ct = idx >> 8;
        int ks = (idx >> 6) & 3;
        int ln = idx & 63;
        int kbase = ks * 32 + (ln >> 4) * 8;
        int c = ct * 16 + (ln & 15);
        half8_t v;
#pragma unroll
        for (int i = 0; i < 8; i++)
            v[i] = (_Float16)Wl[(size_t)(kbase + i) * H + c];
        sB[idx] = v;
    }
    __syncthreads();

    int w = t >> 6, lane = t & 63;
    int lq = lane >> 4, lr = lane & 15;
    int rbase = blockIdx.x * 128 + w * 32;

    floatx4 acc[2][8];
#pragma unroll
    for (int rt = 0; rt < 2; rt++)
#pragma unroll
        for (int ct = 0; ct < 8; ct++) acc[rt][ct] = (floatx4)0.0f;

    float bias[8];
#pragma unroll
    for (int ct = 0; ct < 8; ct++) bias[ct] = bl[ct * 16 + lr];

    int arow[2], xv[2];
#pragma unroll
    for (int rt = 0; rt < 2; rt++) {
        int row = rbase + rt * 16 + lr;
        if (row > N_NODES - 1) row = N_NODES - 1;
        arow[rt] = row;
        if (mode == 0) xv[rt] = xidx[row];
    }

    for (int ks = 0; ks < 4; ks++) {
        int k0 = ks * 32 + lq * 8;
        half8_t a[2];
#pragma unroll
        for (int rt = 0; rt < 2; rt++) {
            float f[8];
            if (mode == 0) {
                const float* p = nemb + (size_t)xv[rt] * H + k0;
                float4 u0 = *(const float4*)p;
                float4 u1 = *(const float4*)(p + 4);
                f[0] = u0.x; f[1] = u0.y; f[2] = u0.z; f[3] = u0.w;
                f[4] = u1.x; f[5] = u1.y; f[6] = u1.z; f[7] = u1.w;
            } else {
                union { float4 f4; __half2 h2[4]; } u;
                u.f4 = *(const float4*)(hsrc + (size_t)arow[rt] * H + k0);
#pragma unroll
                for (int i = 0; i < 4; i++) {
                    float2 d = __half22float2(u.h2[i]);
                    f[2 * i] = d.x; f[2 * i + 1] = d.y;
                }
#pragma unroll
                for (int i = 0; i < 8; i++)
                    f[i] = frelu(f[i] * sScale[k0 + i] + sShift[k0 + i]);
            }
            half8_t av;
#pragma unroll
            for (int i = 0; i < 8; i++) av[i] = (_Float16)f[i];
            a[rt] = av;
        }
#pragma unroll
        for (int ct = 0; ct < 8; ct++) {
            half8_t bf = sB[(ct * 4 + ks) * 64 + lane];
            acc[0][ct] = __builtin_amdgcn_mfma_f32_16x16x32_f16(a[0], bf, acc[0][ct], 0, 0, 0);
            acc[1][ct] = __builtin_amdgcn_mfma_f32_16x16x32_f16(a[1], bf, acc[1][ct], 0, 0, 0);
        }
    }

#pragma unroll
    for (int rt = 0; rt < 2; rt++)
#pragma unroll
        for (int ct = 0; ct < 8; ct++)
#pragma unroll
            for (int r = 0; r < 4; r++) {
                int row = rbase + rt * 16 + lq * 4 + r;
                if (row < N_NODES)
                    xlo[(size_t)row * H + ct * 16 + lr] =
                        __float2half(acc[rt][ct][r] + bias[ct]);
            }
}

// ================= gather aggregation + BN stats =================
// Each wave owns NPW CONTIGUOUS nodes -> one contiguous edge range.
// 2-stage software pipeline over full-8 edge batches (node-boundary-free):
// while batch k's MLP runs, batch k+1's gathers and batch k+2's row-index
// loads are in flight. Node flushes via scalar walk; xl[n]/invdeg[n] for the
// flush are prefetched one node ahead.
__global__ __launch_bounds__(256) void agg_kernel(
    const int* __restrict__ rowptr, const float* __restrict__ ea8,
    const int* __restrict__ rows, const __half2* __restrict__ xh2,
    const float* __restrict__ invdeg, const float* __restrict__ rootl,
    const float* __restrict__ Wel, const float* __restrict__ bel,
    __half2* __restrict__ hpreh, float* __restrict__ colsum,
    float* __restrict__ colsumsq) {
    int t = threadIdx.x;
    int lane = t & 63, wv = t >> 6;
    int c0 = lane * 2;
    float w00 = Wel[0 * H + c0], w01 = Wel[0 * H + c0 + 1];
    float w10 = Wel[1 * H + c0], w11 = Wel[1 * H + c0 + 1];
    float w20 = Wel[2 * H + c0], w21 = Wel[2 * H + c0 + 1];
    float w30 = Wel[3 * H + c0], w31 = Wel[3 * H + c0 + 1];
    float w40 = Wel[4 * H + c0], w41 = Wel[4 * H + c0 + 1];
    float w50 = Wel[5 * H + c0], w51 = Wel[5 * H + c0 + 1];
    float w60 = Wel[6 * H + c0], w61 = Wel[6 * H + c0 + 1];
    float be0 = bel[c0], be1 = bel[c0 + 1];
    float rt0 = rootl[c0], rt1 = rootl[c0 + 1];
    float s0 = 0, s1 = 0, q0 = 0, q1 = 0;

    int wgid = blockIdx.x * 4 + wv;
    int n0 = wgid * NPW;
    bool active = (n0 < N_NODES);
    int n1 = active ? min(n0 + NPW, N_NODES) : n0;
    int n = n0;
    float a0 = 0, a1 = 0;

    __half2 xn_cur = __half2{}, xn_next = __half2{};
    float idg_cur = 0, idg_next = 0;
    int je = 0, e0 = 0, e1 = 0;
    if (active) {
        e0 = __builtin_amdgcn_readfirstlane(rowptr[n0]);
        e1 = __builtin_amdgcn_readfirstlane(rowptr[n1]);
        je = __builtin_amdgcn_readfirstlane(rowptr[n0 + 1]);
        xn_cur = xh2[(size_t)n0 * 64 + lane];
        idg_cur = invdeg[n0];
        int nx = min(n0 + 1, N_NODES - 1);
        xn_next = xh2[(size_t)nx * 64 + lane];
        idg_next = invdeg[nx];
    }

#define MLP_BODY(V0, V1, XG)                                                 \
    {                                                                        \
        float2 xg_ = __half22float2(XG);                                     \
        float m0_ = be0, m1_ = be1;                                          \
        m0_ = fmaf((V0).x, w00, m0_); m1_ = fmaf((V0).x, w01, m1_);          \
        m0_ = fmaf((V0).y, w10, m0_); m1_ = fmaf((V0).y, w11, m1_);          \
        m0_ = fmaf((V0).z, w20, m0_); m1_ = fmaf((V0).z, w21, m1_);          \
        m0_ = fmaf((V0).w, w30, m0_); m1_ = fmaf((V0).w, w31, m1_);          \
        m0_ = fmaf((V1).x, w40, m0_); m1_ = fmaf((V1).x, w41, m1_);          \
        m0_ = fmaf((V1).y, w50, m0_); m1_ = fmaf((V1).y, w51, m1_);          \
        m0_ = fmaf((V1).z, w60, m0_); m1_ = fmaf((V1).z, w61, m1_);          \
        a0 = fmaf(frelu(xg_.x + m0_), (V1).w, a0);                           \
        a1 = fmaf(frelu(xg_.y + m1_), (V1).w, a1);                           \
    }

#define FLUSH()                                                              \
    {                                                                        \
        float2 xnf_ = __half22float2(xn_cur);                                \
        float p0_ = a0 + frelu(xnf_.x + rt0) * idg_cur;                      \
        float p1_ = a1 + frelu(xnf_.y + rt1) * idg_cur;                      \
        hpreh[(size_t)n * 64 + lane] = __float22half2_rn(make_float2(p0_, p1_)); \
        s0 += p0_; s1 += p1_;                                                \
        q0 = fmaf(p0_, p0_, q0); q1 = fmaf(p1_, p1_, q1);                    \
        a0 = 0; a1 = 0;                                                      \
        xn_cur = xn_next; idg_cur = idg_next;                                \
        int nn_ = min(n + 2, N_NODES - 1);                                   \
        xn_next = xh2[(size_t)nn_ * 64 + lane];                              \
        idg_next = invdeg[nn_];                                              \
    }

#define PROCESS(G)                                                           \
    {                                                                        \
        _Pragma("unroll")                                                    \
        for (int i = 0; i < 8; i++) {                                        \
            int jj = j + i;                                                  \
            if (jj < e1) {                                                   \
                while (jj >= je) {                                           \
                    FLUSH();                                                 \
                    n++;                                                     \
                    je = __builtin_amdgcn_readfirstlane(rowptr[n + 1]);      \
                }                                                            \
                const float* ep_ = ea8 + (size_t)jj * 8;                     \
                float4 va_ = *(const float4*)ep_;                            \
                float4 vb_ = *(const float4*)(ep_ + 4);                      \
                MLP_BODY(va_, vb_, G[i]);                                    \
            }                                                                \
        }                                                                    \
    }

    if (active && e1 > e0) {
        int rrA[8], rrB[8];
        __half2 gA[8], gB[8];
        int eclamp = e1 - 1;
#pragma unroll
        for (int i = 0; i < 8; i++)
            rrA[i] = __builtin_amdgcn_readfirstlane(rows[min(e0 + i, eclamp)]);
#pragma unroll
        for (int i = 0; i < 8; i++) gA[i] = xh2[(size_t)rrA[i] * 64 + lane];
#pragma unroll
        for (int i = 0; i < 8; i++)
            rrB[i] = __builtin_amdgcn_readfirstlane(rows[min(e0 + 8 + i, eclamp)]);

        int j = e0;
        while (true) {
            if (j >= e1) break;
            {
                if (j + 8 < e1) {
#pragma unroll
                    for (int i = 0; i < 8; i++) gB[i] = xh2[(size_t)rrB[i] * 64 + lane];
#pragma unroll
                    for (int i = 0; i < 8; i++)
                        rrA[i] = __builtin_amdgcn_readfirstlane(rows[min(j + 16 + i, eclamp)]);
                }
                PROCESS(gA);
                j += 8;
            }
            if (j >= e1) break;
            {
                if (j + 8 < e1) {
#pragma unroll
                    for (int i = 0; i < 8; i++) gA[i] = xh2[(size_t)rrA[i] * 64 + lane];
#pragma unroll
                    for (int i = 0; i < 8; i++)
                        rrB[i] = __builtin_amdgcn_readfirstlane(rows[min(j + 16 + i, eclamp)]);
                }
                PROCESS(gB);
                j += 8;
            }
        }
    }
    // flush remaining nodes in range (last node + any trailing empty nodes)
    while (n < n1) {
        FLUSH();
        n++;
    }
#undef PROCESS
#undef FLUSH
#undef MLP_BODY

    __shared__ float red[4][H];
    red[wv][c0] = s0; red[wv][c0 + 1] = s1;
    __syncthreads();
    if (wv == 0) {
        float t0 = red[0][c0] + red[1][c0] + red[2][c0] + red[3][c0];
        float t1 = red[0][c0 + 1] + red[1][c0 + 1] + red[2][c0 + 1] + red[3][c0 + 1];
        unsafeAtomicAdd(&colsum[c0], t0);
        unsafeAtomicAdd(&colsum[c0 + 1], t1);
    }
    __syncthreads();
    red[wv][c0] = q0; red[wv][c0 + 1] = q1;
    __syncthreads();
    if (wv == 0) {
        float t0 = red[0][c0] + red[1][c0] + red[2][c0] + red[3][c0];
        float t1 = red[0][c0 + 1] + red[1][c0 + 1] + red[2][c0 + 1] + red[3][c0 + 1];
        unsafeAtomicAdd(&colsumsq[c0], t0);
        unsafeAtomicAdd(&colsumsq[c0 + 1], t1);
    }
}

// ================= pool (applies final BN in-kernel, fp16 input) =================
__global__ __launch_bounds__(256) void pool_kernel(const __half2* __restrict__ hh,
                                                   const int* __restrict__ batch,
                                                   const float* __restrict__ colsum_p,
                                                   const float* __restrict__ colsumsq_p,
                                                   const float* __restrict__ gamma_p,
                                                   const float* __restrict__ beta_p,
                                                   float* __restrict__ pooled,
                                                   float* __restrict__ cnt) {
    __shared__ float sScale[H], sShift[H];
    int t = threadIdx.x;
    if (t < H) {
        float mean = colsum_p[t] * (1.0f / N_NODES);
        float var = colsumsq_p[t] * (1.0f / N_NODES) - mean * mean;
        float s = gamma_p[t] * rsqrtf(var + BN_EPS);
        sScale[t] = s;
        sShift[t] = beta_p[t] - mean * s;
    }
    __syncthreads();
    int cg = t & 63, rg = t >> 6;
    int c0 = cg * 2;
    float sc0 = sScale[c0], sc1 = sScale[c0 + 1];
    float sh0 = sShift[c0], sh1 = sShift[c0 + 1];
    int per = (N_NODES + gridDim.x - 1) / gridDim.x;
    int rstart = blockIdx.x * per;
    int rend = min(rstart + per, N_NODES);
    float a0 = 0, a1 = 0, runc = 0.0f;
    int cur = -1;
    for (int rowi = rstart + rg; rowi < rend; rowi += 4) {
        int g = batch[rowi];
        if (g != cur) {
            if (cur >= 0) {
                unsafeAtomicAdd(&pooled[(size_t)cur * H + c0 + 0], a0);
                unsafeAtomicAdd(&pooled[(size_t)cur * H + c0 + 1], a1);
                if (cg == 0) unsafeAtomicAdd(&cnt[cur], runc);
            }
            cur = g; a0 = 0; a1 = 0; runc = 0.0f;
        }
        float2 v = __half22float2(hh[(size_t)rowi * 64 + cg]);
        a0 += v.x * sc0 + sh0;
        a1 += v.y * sc1 + sh1;
        runc += 1.0f;
    }
    if (cur >= 0) {
        unsafeAtomicAdd(&pooled[(size_t)cur * H + c0 + 0], a0);
        unsafeAtomicAdd(&pooled[(size_t)cur * H + c0 + 1], a1);
        if (cg == 0) unsafeAtomicAdd(&cnt[cur], runc);
    }
}

__global__ __launch_bounds__(128) void final_gemm(const float* __restrict__ pooled,
                                                  const float* __restrict__ cnt,
                                                  const float* __restrict__ Wout,
                                                  const float* __restrict__ bout,
                                                  float* __restrict__ out) {
    __shared__ float sh[H];
    int g = blockIdx.x;
    int o = threadIdx.x;
    float c = fmaxf(cnt[g], 1.0f);
    sh[o] = pooled[(size_t)g * H + o] / c;
    __syncthreads();
    float acc = bout[o];
#pragma unroll 8
    for (int k = 0; k < H; k++) acc += sh[k] * Wout[(size_t)k * OUT_F + o];
    out[(size_t)g * OUT_F + o] = acc;
}

extern "C" void kernel_launch(void* const* d_in, const int* in_sizes, int n_in,
                              void* d_out, int out_size, void* d_ws, size_t ws_size,
                              hipStream_t stream) {
    const int*   x     = (const int*)d_in[0];
    const int*   ei    = (const int*)d_in[1];
    const float* ea    = (const float*)d_in[2];
    const int*   batch = (const int*)d_in[3];
    const float* nemb  = (const float*)d_in[4];
    const float* W     = (const float*)d_in[5];
    const float* b     = (const float*)d_in[6];
    const float* We    = (const float*)d_in[7];
    const float* be    = (const float*)d_in[8];
    const float* root  = (const float*)d_in[9];
    const float* gamma = (const float*)d_in[10];
    const float* beta  = (const float*)d_in[11];
    const float* Wout  = (const float*)d_in[12];
    const float* bout  = (const float*)d_in[13];
    float* out = (float*)d_out;

    const int* erow = ei;
    const int* ecol = ei + N_EDGES;

    float* ws = (float*)d_ws;
    size_t NH = (size_t)N_NODES * H;
    float* ea8    = ws;                                  // E*8 floats
    int*   rows   = (int*)(ea8 + (size_t)N_EDGES * 8);   // E ints
    float* hslot  = (float*)(rows + N_EDGES);            // NH/2 floats (fp16 hpre)
    __half* hpreh = (__half*)hslot;
    float* xslot  = hslot + NH / 2;                      // NH/2 floats (fp16 xl)
    __half* xlh   = (__half*)xslot;
    int*   rowptr = (int*)(xslot + NH / 2);              // N+1 (+pad)
    float* dis    = (float*)(rowptr + N_NODES + 4);
    float* invdeg = dis + N_NODES;
    float* colsumAll = invdeg + N_NODES;                 // L*2*H floats
    float* pooled   = colsumAll + (size_t)L_LAYERS * 2 * H;
    float* cnt      = pooled + (size_t)G_GRAPHS * H;
    int*   blocksum = (int*)(cnt + G_GRAPHS);            // 128
    int*   blockoff = blocksum + 128;                    // 128

    // preprocessing temps alias into hpre region (hpre first written in layer 0 agg)
    int* degcnt = (int*)hslot;
    int* hist   = degcnt + N_NODES;
    int* cursor = hist + N_NODES;

    hipMemsetAsync(degcnt, 0, 2 * N_NODES * sizeof(int), stream);
    hipMemsetAsync(colsumAll, 0, (size_t)L_LAYERS * 2 * H * sizeof(float), stream);
    hipLaunchKernelGGL(count_kernel, dim3(N_EDGES / 256), dim3(256), 0, stream,
                       erow, ecol, degcnt, hist);
    hipLaunchKernelGGL(finish_deg, dim3((N_NODES + 255) / 256), dim3(256), 0, stream,
                       degcnt, dis, invdeg);
    hipLaunchKernelGGL(scan_part, dim3(SCAN_BLOCKS), dim3(1024), 0, stream,
                       hist, rowptr, blocksum);
    hipLaunchKernelGGL(scan_block, dim3(1), dim3(128), 0, stream,
                       blocksum, blockoff, rowptr);
    hipLaunchKernelGGL(scan_add, dim3(SCAN_BLOCKS), dim3(1024), 0, stream,
                       rowptr, blockoff, cursor);
    hipLaunchKernelGGL(scatter_kernel, dim3(N_EDGES / 256), dim3(256), 0, stream,
                       erow, ecol, ea, dis, cursor, ea8, rows);

    for (int l = 0; l < L_LAYERS; l++) {
        const float* cs_prev = colsumAll + (size_t)(l - 1) * 2 * H;  // unused when l==0
        hipLaunchKernelGGL(gemm_xl, dim3((N_NODES + 127) / 128), dim3(256), 0, stream,
                           hpreh, x, nemb,
                           (l == 0) ? colsumAll : cs_prev,
                           (l == 0) ? colsumAll : cs_prev + H,
                           gamma + (size_t)(l ? l - 1 : 0) * H,
                           beta + (size_t)(l ? l - 1 : 0) * H,
                           W + (size_t)l * H * H, b + (size_t)l * H, xlh,
                           (l == 0) ? 0 : 1);
        float* cs = colsumAll + (size_t)l * 2 * H;
        hipLaunchKernelGGL(agg_kernel, dim3(AGG_BLOCKS), dim3(256), 0, stream,
                           rowptr, ea8, rows, (const __half2*)xlh, invdeg,
                           root + (size_t)l * H, We + (size_t)l * 7 * H, be + (size_t)l * H,
                           (__half2*)hpreh, cs, cs + H);
    }

    hipMemsetAsync(pooled, 0, ((size_t)G_GRAPHS * H + G_GRAPHS) * sizeof(float), stream);
    {
        const float* cs4 = colsumAll + (size_t)(L_LAYERS - 1) * 2 * H;
        hipLaunchKernelGGL(pool_kernel, dim3(256), dim3(256), 0, stream,
                           (const __half2*)hpreh, batch, cs4, cs4 + H,
                           gamma + (size_t)(L_LAYERS - 1) * H,
                           beta + (size_t)(L_LAYERS - 1) * H, pooled, cnt);
    }
    hipLaunchKernelGGL(final_gemm, dim3(G_GRAPHS), dim3(OUT_F), 0, stream,
                       pooled, cnt, Wout, bout, out);
}

// Round 9
// 1315.802 us; speedup vs baseline: 1.3105x; 1.3105x over previous
//
#include <hip/hip_runtime.h>
#include <hip/hip_fp16.h>
#include <cstdint>
#include <cstddef>

#define N_NODES 100000
#define N_EDGES 1600000
#define H 128
#define L_LAYERS 5
#define G_GRAPHS 128
#define OUT_F 128
#define BN_EPS 1e-5f
#define SCAN_BLOCKS 98   // ceil(100000/1024)

typedef _Float16 half8_t __attribute__((ext_vector_type(8)));
typedef float floatx4 __attribute__((ext_vector_type(4)));

__device__ __forceinline__ float frelu(float x) { return fmaxf(x, 0.0f); }

// ================= preprocessing =================

__global__ void count_kernel(const int* __restrict__ erow, const int* __restrict__ ecol,
                             int* __restrict__ degcnt, int* __restrict__ hist) {
    int e = blockIdx.x * 256 + threadIdx.x;  // E divisible by 256
    atomicAdd(&degcnt[erow[e]], 1);
    atomicAdd(&hist[ecol[e]], 1);
}

__global__ void finish_deg(const int* __restrict__ degcnt, float* __restrict__ dis,
                           float* __restrict__ invdeg) {
    int i = blockIdx.x * 256 + threadIdx.x;
    if (i < N_NODES) {
        float d = (float)degcnt[i] + 1.0f;
        dis[i] = rsqrtf(d);
        invdeg[i] = 1.0f / d;
    }
}

// ---- two-level scan ----
__global__ __launch_bounds__(1024) void scan_part(const int* __restrict__ hist,
                                                  int* __restrict__ rowptr,
                                                  int* __restrict__ blocksum) {
    int t = threadIdx.x;
    int i = blockIdx.x * 1024 + t;
    int orig = (i < N_NODES) ? hist[i] : 0;
    int v = orig;
#pragma unroll
    for (int off = 1; off < 64; off <<= 1) {
        int u = __shfl_up(v, off);
        if ((t & 63) >= off) v += u;
    }
    __shared__ int wsum[16];
    int wid = t >> 6;
    if ((t & 63) == 63) wsum[wid] = v;
    __syncthreads();
    int woff = 0;
#pragma unroll
    for (int w = 0; w < 16; w++)
        if (w < wid) woff += wsum[w];
    int incl = v + woff;
    if (i < N_NODES) rowptr[i] = incl - orig;
    if (t == 1023) blocksum[blockIdx.x] = incl;
}

__global__ __launch_bounds__(128) void scan_block(const int* __restrict__ blocksum,
                                                  int* __restrict__ blockoff,
                                                  int* __restrict__ rowptr) {
    int t = threadIdx.x;
    int orig = (t < SCAN_BLOCKS) ? blocksum[t] : 0;
    int v = orig;
#pragma unroll
    for (int off = 1; off < 64; off <<= 1) {
        int u = __shfl_up(v, off);
        if ((t & 63) >= off) v += u;
    }
    __shared__ int w0;
    if (t == 63) w0 = v;
    __syncthreads();
    if (t >= 64) v += w0;
    if (t < SCAN_BLOCKS) blockoff[t] = v - orig;
    if (t == 0) rowptr[N_NODES] = N_EDGES;
}

__global__ __launch_bounds__(1024) void scan_add(int* __restrict__ rowptr,
                                                 const int* __restrict__ blockoff,
                                                 int* __restrict__ cursor) {
    int i = blockIdx.x * 1024 + threadIdx.x;
    if (i < N_NODES) {
        int v = rowptr[i] + blockoff[blockIdx.x];
        rowptr[i] = v;
        cursor[i] = v;
    }
}

// permute edge payloads into col-sorted order, fp16-compressed:
//   eah[pos] = half8 {a0..a6, norm}   rows[pos] = row
__global__ void scatter_kernel(const int* __restrict__ erow, const int* __restrict__ ecol,
                               const float* __restrict__ ea, const float* __restrict__ dis,
                               int* __restrict__ cursor,
                               float4* __restrict__ eah, int* __restrict__ rows) {
    int e = blockIdx.x * 256 + threadIdx.x;
    int c = ecol[e];
    int r = erow[e];
    float nrm = dis[r] * dis[c];
    int pos = atomicAdd(&cursor[c], 1);
    const float* p = ea + (size_t)e * 7;
    union { float4 f4; __half2 h2[4]; } u;
    u.h2[0] = __float22half2_rn(make_float2(p[0], p[1]));
    u.h2[1] = __float22half2_rn(make_float2(p[2], p[3]));
    u.h2[2] = __float22half2_rn(make_float2(p[4], p[5]));
    u.h2[3] = __float22half2_rn(make_float2(p[6], nrm));
    eah[pos] = u.f4;
    rows[pos] = r;
}

// ================= xl = act(h) @ W + b  via MFMA f16 =================
__global__ __launch_bounds__(256) void gemm_xl(const __half* __restrict__ hsrc,
                                               const int* __restrict__ xidx,
                                               const float* __restrict__ nemb,
                                               const float* __restrict__ colsum_p,
                                               const float* __restrict__ colsumsq_p,
                                               const float* __restrict__ gamma_p,
                                               const float* __restrict__ beta_p,
                                               const float* __restrict__ Wl,
                                               const float* __restrict__ bl,
                                               __half* __restrict__ xlo, int mode) {
    __shared__ half8_t sB[2048];          // [ct][ks][lane] fragments, 32 KB
    __shared__ float sScale[H], sShift[H];
    int t = threadIdx.x;
    if (mode == 1 && t < H) {
        float mean = colsum_p[t] * (1.0f / N_NODES);
        float var = colsumsq_p[t] * (1.0f / N_NODES) - mean * mean;
        float s = gamma_p[t] * rsqrtf(var + BN_EPS);
        sScale[t] = s;
        sShift[t] = beta_p[t] - mean * s;
    }
    // stage W as B-fragments
    for (int idx = t; idx < 2048; idx += 256) {
        int ct = idx >> 8;
        int ks = (idx >> 6) & 3;
        int ln = idx & 63;
        int kbase = ks * 32 + (ln >> 4) * 8;
        int c = ct * 16 + (ln & 15);
        half8_t v;
#pragma unroll
        for (int i = 0; i < 8; i++)
            v[i] = (_Float16)Wl[(size_t)(kbase + i) * H + c];
        sB[idx] = v;
    }
    __syncthreads();

    int w = t >> 6, lane = t & 63;
    int lq = lane >> 4, lr = lane & 15;
    int rbase = blockIdx.x * 128 + w * 32;

    floatx4 acc[2][8];
#pragma unroll
    for (int rt = 0; rt < 2; rt++)
#pragma unroll
        for (int ct = 0; ct < 8; ct++) acc[rt][ct] = (floatx4)0.0f;

    float bias[8];
#pragma unroll
    for (int ct = 0; ct < 8; ct++) bias[ct] = bl[ct * 16 + lr];

    int arow[2], xv[2];
#pragma unroll
    for (int rt = 0; rt < 2; rt++) {
        int row = rbase + rt * 16 + lr;
        if (row > N_NODES - 1) row = N_NODES - 1;
        arow[rt] = row;
        if (mode == 0) xv[rt] = xidx[row];
    }

    for (int ks = 0; ks < 4; ks++) {
        int k0 = ks * 32 + lq * 8;
        half8_t a[2];
#pragma unroll
        for (int rt = 0; rt < 2; rt++) {
            float f[8];
            if (mode == 0) {
                const float* p = nemb + (size_t)xv[rt] * H + k0;
                float4 u0 = *(const float4*)p;
                float4 u1 = *(const float4*)(p + 4);
                f[0] = u0.x; f[1] = u0.y; f[2] = u0.z; f[3] = u0.w;
                f[4] = u1.x; f[5] = u1.y; f[6] = u1.z; f[7] = u1.w;
            } else {
                union { float4 f4; __half2 h2[4]; } u;
                u.f4 = *(const float4*)(hsrc + (size_t)arow[rt] * H + k0);
#pragma unroll
                for (int i = 0; i < 4; i++) {
                    float2 d = __half22float2(u.h2[i]);
                    f[2 * i] = d.x; f[2 * i + 1] = d.y;
                }
#pragma unroll
                for (int i = 0; i < 8; i++)
                    f[i] = frelu(f[i] * sScale[k0 + i] + sShift[k0 + i]);
            }
            half8_t av;
#pragma unroll
            for (int i = 0; i < 8; i++) av[i] = (_Float16)f[i];
            a[rt] = av;
        }
#pragma unroll
        for (int ct = 0; ct < 8; ct++) {
            half8_t bf = sB[(ct * 4 + ks) * 64 + lane];
            acc[0][ct] = __builtin_amdgcn_mfma_f32_16x16x32_f16(a[0], bf, acc[0][ct], 0, 0, 0);
            acc[1][ct] = __builtin_amdgcn_mfma_f32_16x16x32_f16(a[1], bf, acc[1][ct], 0, 0, 0);
        }
    }

#pragma unroll
    for (int rt = 0; rt < 2; rt++)
#pragma unroll
        for (int ct = 0; ct < 8; ct++)
#pragma unroll
            for (int r = 0; r < 4; r++) {
                int row = rbase + rt * 16 + lq * 4 + r;
                if (row < N_NODES)
                    xlo[(size_t)row * H + ct * 16 + lr] =
                        __float2half(acc[rt][ct][r] + bias[ct]);
            }
}

// ================= gather aggregation + BN stats =================
// wave per node (strided); lane owns cols {2*lane, 2*lane+1}; xl gathered as
// half2; hpre written as half2; payload fp16 (16B/edge). 16/8/4/1 batch tiers.
__global__ __launch_bounds__(256) void agg_kernel(
    const int* __restrict__ rowptr, const float4* __restrict__ eah,
    const int* __restrict__ rows, const __half2* __restrict__ xh2,
    const float* __restrict__ invdeg, const float* __restrict__ rootl,
    const float* __restrict__ Wel, const float* __restrict__ bel,
    __half2* __restrict__ hpreh, float* __restrict__ colsum,
    float* __restrict__ colsumsq) {
    int t = threadIdx.x;
    int lane = t & 63, wv = t >> 6;
    int c0 = lane * 2;
    float w00 = Wel[0 * H + c0], w01 = Wel[0 * H + c0 + 1];
    float w10 = Wel[1 * H + c0], w11 = Wel[1 * H + c0 + 1];
    float w20 = Wel[2 * H + c0], w21 = Wel[2 * H + c0 + 1];
    float w30 = Wel[3 * H + c0], w31 = Wel[3 * H + c0 + 1];
    float w40 = Wel[4 * H + c0], w41 = Wel[4 * H + c0 + 1];
    float w50 = Wel[5 * H + c0], w51 = Wel[5 * H + c0 + 1];
    float w60 = Wel[6 * H + c0], w61 = Wel[6 * H + c0 + 1];
    float be0 = bel[c0], be1 = bel[c0 + 1];
    float rt0 = rootl[c0], rt1 = rootl[c0 + 1];
    float s0 = 0, s1 = 0, q0 = 0, q1 = 0;

    // payload half8 {a0..a6, norm} + gathered half2 -> accumulate
#define MLP_BODY(PV, XG)                                                     \
    {                                                                        \
        const __half2* ph_ = (const __half2*)&(PV);                          \
        float2 A01_ = __half22float2(ph_[0]);                                \
        float2 A23_ = __half22float2(ph_[1]);                                \
        float2 A45_ = __half22float2(ph_[2]);                                \
        float2 A6N_ = __half22float2(ph_[3]);                                \
        float2 xg_ = __half22float2(XG);                                     \
        float m0_ = be0, m1_ = be1;                                          \
        m0_ = fmaf(A01_.x, w00, m0_); m1_ = fmaf(A01_.x, w01, m1_);          \
        m0_ = fmaf(A01_.y, w10, m0_); m1_ = fmaf(A01_.y, w11, m1_);          \
        m0_ = fmaf(A23_.x, w20, m0_); m1_ = fmaf(A23_.x, w21, m1_);          \
        m0_ = fmaf(A23_.y, w30, m0_); m1_ = fmaf(A23_.y, w31, m1_);          \
        m0_ = fmaf(A45_.x, w40, m0_); m1_ = fmaf(A45_.x, w41, m1_);          \
        m0_ = fmaf(A45_.y, w50, m0_); m1_ = fmaf(A45_.y, w51, m1_);          \
        m0_ = fmaf(A6N_.x, w60, m0_); m1_ = fmaf(A6N_.x, w61, m1_);          \
        a0 = fmaf(frelu(xg_.x + m0_), A6N_.y, a0);                           \
        a1 = fmaf(frelu(xg_.y + m1_), A6N_.y, a1);                           \
    }

    for (int n_ = blockIdx.x * 4 + wv; n_ < N_NODES; n_ += gridDim.x * 4) {
        int n = __builtin_amdgcn_readfirstlane(n_);
        int jb = __builtin_amdgcn_readfirstlane(rowptr[n]);
        int je = __builtin_amdgcn_readfirstlane(rowptr[n + 1]);
        float a0 = 0, a1 = 0;
        int j = jb;
        for (; j + 16 <= je; j += 16) {
            int rr[16];
#pragma unroll
            for (int i = 0; i < 16; i++) rr[i] = rows[j + i];
            __half2 g[16];
#pragma unroll
            for (int i = 0; i < 16; i++) g[i] = xh2[(size_t)rr[i] * 64 + lane];
#pragma unroll
            for (int i = 0; i < 16; i++) {
                float4 pv = eah[j + i];
                MLP_BODY(pv, g[i]);
            }
        }
        if (j + 8 <= je) {
            int rr[8];
#pragma unroll
            for (int i = 0; i < 8; i++) rr[i] = rows[j + i];
            __half2 g[8];
#pragma unroll
            for (int i = 0; i < 8; i++) g[i] = xh2[(size_t)rr[i] * 64 + lane];
#pragma unroll
            for (int i = 0; i < 8; i++) {
                float4 pv = eah[j + i];
                MLP_BODY(pv, g[i]);
            }
            j += 8;
        }
        if (j + 4 <= je) {
            int rr[4];
#pragma unroll
            for (int i = 0; i < 4; i++) rr[i] = rows[j + i];
            __half2 g[4];
#pragma unroll
            for (int i = 0; i < 4; i++) g[i] = xh2[(size_t)rr[i] * 64 + lane];
#pragma unroll
            for (int i = 0; i < 4; i++) {
                float4 pv = eah[j + i];
                MLP_BODY(pv, g[i]);
            }
            j += 4;
        }
        for (; j < je; j++) {
            int r_ = rows[j];
            __half2 g_ = xh2[(size_t)r_ * 64 + lane];
            float4 pv = eah[j];
            MLP_BODY(pv, g_);
        }
        float2 xn = __half22float2(xh2[(size_t)n * 64 + lane]);
        float id = invdeg[n];
        float p0 = a0 + frelu(xn.x + rt0) * id;
        float p1 = a1 + frelu(xn.y + rt1) * id;
        hpreh[(size_t)n * 64 + lane] = __float22half2_rn(make_float2(p0, p1));
        s0 += p0; s1 += p1;
        q0 = fmaf(p0, p0, q0); q1 = fmaf(p1, p1, q1);
    }
#undef MLP_BODY

    __shared__ float red[4][H];
    red[wv][c0] = s0; red[wv][c0 + 1] = s1;
    __syncthreads();
    if (wv == 0) {
        float t0 = red[0][c0] + red[1][c0] + red[2][c0] + red[3][c0];
        float t1 = red[0][c0 + 1] + red[1][c0 + 1] + red[2][c0 + 1] + red[3][c0 + 1];
        unsafeAtomicAdd(&colsum[c0], t0);
        unsafeAtomicAdd(&colsum[c0 + 1], t1);
    }
    __syncthreads();
    red[wv][c0] = q0; red[wv][c0 + 1] = q1;
    __syncthreads();
    if (wv == 0) {
        float t0 = red[0][c0] + red[1][c0] + red[2][c0] + red[3][c0];
        float t1 = red[0][c0 + 1] + red[1][c0 + 1] + red[2][c0 + 1] + red[3][c0 + 1];
        unsafeAtomicAdd(&colsumsq[c0], t0);
        unsafeAtomicAdd(&colsumsq[c0 + 1], t1);
    }
}

// ================= pool (applies final BN in-kernel, fp16 input) =================
__global__ __launch_bounds__(256) void pool_kernel(const __half2* __restrict__ hh,
                                                   const int* __restrict__ batch,
                                                   const float* __restrict__ colsum_p,
                                                   const float* __restrict__ colsumsq_p,
                                                   const float* __restrict__ gamma_p,
                                                   const float* __restrict__ beta_p,
                                                   float* __restrict__ pooled,
                                                   float* __restrict__ cnt) {
    __shared__ float sScale[H], sShift[H];
    int t = threadIdx.x;
    if (t < H) {
        float mean = colsum_p[t] * (1.0f / N_NODES);
        float var = colsumsq_p[t] * (1.0f / N_NODES) - mean * mean;
        float s = gamma_p[t] * rsqrtf(var + BN_EPS);
        sScale[t] = s;
        sShift[t] = beta_p[t] - mean * s;
    }
    __syncthreads();
    int cg = t & 63, rg = t >> 6;
    int c0 = cg * 2;
    float sc0 = sScale[c0], sc1 = sScale[c0 + 1];
    float sh0 = sShift[c0], sh1 = sShift[c0 + 1];
    int per = (N_NODES + gridDim.x - 1) / gridDim.x;
    int rstart = blockIdx.x * per;
    int rend = min(rstart + per, N_NODES);
    float a0 = 0, a1 = 0, runc = 0.0f;
    int cur = -1;
    for (int rowi = rstart + rg; rowi < rend; rowi += 4) {
        int g = batch[rowi];
        if (g != cur) {
            if (cur >= 0) {
                unsafeAtomicAdd(&pooled[(size_t)cur * H + c0 + 0], a0);
                unsafeAtomicAdd(&pooled[(size_t)cur * H + c0 + 1], a1);
                if (cg == 0) unsafeAtomicAdd(&cnt[cur], runc);
            }
            cur = g; a0 = 0; a1 = 0; runc = 0.0f;
        }
        float2 v = __half22float2(hh[(size_t)rowi * 64 + cg]);
        a0 += v.x * sc0 + sh0;
        a1 += v.y * sc1 + sh1;
        runc += 1.0f;
    }
    if (cur >= 0) {
        unsafeAtomicAdd(&pooled[(size_t)cur * H + c0 + 0], a0);
        unsafeAtomicAdd(&pooled[(size_t)cur * H + c0 + 1], a1);
        if (cg == 0) unsafeAtomicAdd(&cnt[cur], runc);
    }
}

__global__ __launch_bounds__(128) void final_gemm(const float* __restrict__ pooled,
                                                  const float* __restrict__ cnt,
                                                  const float* __restrict__ Wout,
                                                  const float* __restrict__ bout,
                                                  float* __restrict__ out) {
    __shared__ float sh[H];
    int g = blockIdx.x;
    int o = threadIdx.x;
    float c = fmaxf(cnt[g], 1.0f);
    sh[o] = pooled[(size_t)g * H + o] / c;
    __syncthreads();
    float acc = bout[o];
#pragma unroll 8
    for (int k = 0; k < H; k++) acc += sh[k] * Wout[(size_t)k * OUT_F + o];
    out[(size_t)g * OUT_F + o] = acc;
}

extern "C" void kernel_launch(void* const* d_in, const int* in_sizes, int n_in,
                              void* d_out, int out_size, void* d_ws, size_t ws_size,
                              hipStream_t stream) {
    const int*   x     = (const int*)d_in[0];
    const int*   ei    = (const int*)d_in[1];
    const float* ea    = (const float*)d_in[2];
    const int*   batch = (const int*)d_in[3];
    const float* nemb  = (const float*)d_in[4];
    const float* W     = (const float*)d_in[5];
    const float* b     = (const float*)d_in[6];
    const float* We    = (const float*)d_in[7];
    const float* be    = (const float*)d_in[8];
    const float* root  = (const float*)d_in[9];
    const float* gamma = (const float*)d_in[10];
    const float* beta  = (const float*)d_in[11];
    const float* Wout  = (const float*)d_in[12];
    const float* bout  = (const float*)d_in[13];
    float* out = (float*)d_out;

    const int* erow = ei;
    const int* ecol = ei + N_EDGES;

    float* ws = (float*)d_ws;
    size_t NH = (size_t)N_NODES * H;
    float4* eah   = (float4*)ws;                         // E float4 (fp16 payload)
    int*   rows   = (int*)(eah + N_EDGES);               // E ints
    float* hslot  = (float*)(rows + N_EDGES);            // NH/2 floats (fp16 hpre)
    __half* hpreh = (__half*)hslot;
    float* xslot  = hslot + NH / 2;                      // NH/2 floats (fp16 xl)
    __half* xlh   = (__half*)xslot;
    int*   rowptr = (int*)(xslot + NH / 2);              // N+1 (+pad)
    float* dis    = (float*)(rowptr + N_NODES + 4);
    float* invdeg = dis + N_NODES;
    float* colsumAll = invdeg + N_NODES;                 // L*2*H floats
    float* pooled   = colsumAll + (size_t)L_LAYERS * 2 * H;
    float* cnt      = pooled + (size_t)G_GRAPHS * H;
    int*   blocksum = (int*)(cnt + G_GRAPHS);            // 128
    int*   blockoff = blocksum + 128;                    // 128

    // preprocessing temps alias into hpre region (hpre first written in layer 0 agg)
    int* degcnt = (int*)hslot;
    int* hist   = degcnt + N_NODES;
    int* cursor = hist + N_NODES;

    hipMemsetAsync(degcnt, 0, 2 * N_NODES * sizeof(int), stream);
    hipMemsetAsync(colsumAll, 0, (size_t)L_LAYERS * 2 * H * sizeof(float), stream);
    hipLaunchKernelGGL(count_kernel, dim3(N_EDGES / 256), dim3(256), 0, stream,
                       erow, ecol, degcnt, hist);
    hipLaunchKernelGGL(finish_deg, dim3((N_NODES + 255) / 256), dim3(256), 0, stream,
                       degcnt, dis, invdeg);
    hipLaunchKernelGGL(scan_part, dim3(SCAN_BLOCKS), dim3(1024), 0, stream,
                       hist, rowptr, blocksum);
    hipLaunchKernelGGL(scan_block, dim3(1), dim3(128), 0, stream,
                       blocksum, blockoff, rowptr);
    hipLaunchKernelGGL(scan_add, dim3(SCAN_BLOCKS), dim3(1024), 0, stream,
                       rowptr, blockoff, cursor);
    hipLaunchKernelGGL(scatter_kernel, dim3(N_EDGES / 256), dim3(256), 0, stream,
                       erow, ecol, ea, dis, cursor, eah, rows);

    for (int l = 0; l < L_LAYERS; l++) {
        const float* cs_prev = colsumAll + (size_t)(l - 1) * 2 * H;  // unused when l==0
        hipLaunchKernelGGL(gemm_xl, dim3((N_NODES + 127) / 128), dim3(256), 0, stream,
                           hpreh, x, nemb,
                           (l == 0) ? colsumAll : cs_prev,
                           (l == 0) ? colsumAll : cs_prev + H,
                           gamma + (size_t)(l ? l - 1 : 0) * H,
                           beta + (size_t)(l ? l - 1 : 0) * H,
                           W + (size_t)l * H * H, b + (size_t)l * H, xlh,
                           (l == 0) ? 0 : 1);
        float* cs = colsumAll + (size_t)l * 2 * H;
        hipLaunchKernelGGL(agg_kernel, dim3(2048), dim3(256), 0, stream,
                           rowptr, eah, rows, (const __half2*)xlh, invdeg,
                           root + (size_t)l * H, We + (size_t)l * 7 * H, be + (size_t)l * H,
                           (__half2*)hpreh, cs, cs + H);
    }

    hipMemsetAsync(pooled, 0, ((size_t)G_GRAPHS * H + G_GRAPHS) * sizeof(float), stream);
    {
        const float* cs4 = colsumAll + (size_t)(L_LAYERS - 1) * 2 * H;
        hipLaunchKernelGGL(pool_kernel, dim3(256), dim3(256), 0, stream,
                           (const __half2*)hpreh, batch, cs4, cs4 + H,
                           gamma + (size_t)(L_LAYERS - 1) * H,
                           beta + (size_t)(L_LAYERS - 1) * H, pooled, cnt);
    }
    hipLaunchKernelGGL(final_gemm, dim3(G_GRAPHS), dim3(OUT_F), 0, stream,
                       pooled, cnt, Wout, bout, out);
}